// Round 1
// baseline (247.227 us; speedup 1.0000x reference)
//
#include <hip/hip_runtime.h>
#include <hip/hip_cooperative_groups.h>

namespace cg = cooperative_groups;

static constexpr int    N            = 2048;
static constexpr int    NBLK         = 256;
static constexpr int    NTHR         = 256;
static constexpr int    ROWS_PER_BLK = N / NBLK;   // 8
static constexpr int    COLS_PER_THR = N / NTHR;   // 8
static constexpr double D_MASS       = 0.9;
static constexpr double D_TOL        = 0.01;
static constexpr int    NITER        = 50;

struct Ws {
    double a_sum;
    double b_sum;
    double err;
    int    done;
    int    _pad;
    double blkpart[NBLK];
    double errParts[NBLK];
    double dotParts[8];
    float  U[N];
    float  V[N];
    float  Up[N];
    float  Vp[N];
    float  row_prev[N];
    float  col_prev[N];
    float  partialT[NBLK * N];   // 2 MB column partial sums
};

__device__ __forceinline__ double block_reduce_sum(double v) {
    __shared__ double red[4];
    for (int off = 32; off > 0; off >>= 1) v += __shfl_xor(v, off, 64);
    const int wave = threadIdx.x >> 6;
    const int lane = threadIdx.x & 63;
    __syncthreads();                 // protect red[] reuse across calls
    if (lane == 0) red[wave] = v;
    __syncthreads();
    return red[0] + red[1] + red[2] + red[3];
}

__global__ void __launch_bounds__(NTHR, 1)
epot_kernel(const float* __restrict__ C, const float* __restrict__ a,
            const float* __restrict__ b, float* __restrict__ K,
            Ws* __restrict__ ws) {
    cg::grid_group grid = cg::this_grid();
    const int tid  = threadIdx.x;
    const int bid  = blockIdx.x;
    const int gtid = bid * NTHR + tid;
    const int wave = tid >> 6;
    const int lane = tid & 63;
    const int r0   = bid * ROWS_PER_BLK;
    const size_t ebase = (size_t)r0 * N;

    // ---------------- precompute: K0 = exp(-10 C), sums, init state ----
    {
        double ps = 0.0;
        for (int k = tid; k < ROWS_PER_BLK * N; k += NTHR) {
            float e = expf(-10.0f * C[ebase + k]);
            K[ebase + k] = e;
            ps += (double)e;
        }
        double bs = block_reduce_sum(ps);
        if (tid == 0) ws->blkpart[bid] = bs;
        if (bid == 0) {
            double s = 0.0;
            for (int k = tid; k < N; k += NTHR) s += (double)a[k];
            double t = block_reduce_sum(s);
            if (tid == 0) ws->a_sum = t;
        } else if (bid == 1) {
            double s = 0.0;
            for (int k = tid; k < N; k += NTHR) s += (double)b[k];
            double t = block_reduce_sum(s);
            if (tid == 0) ws->b_sum = t;
        }
        if (gtid < N) {
            ws->U[gtid] = 1.0f; ws->V[gtid] = 1.0f;
            ws->row_prev[gtid] = 1.0f; ws->col_prev[gtid] = 1.0f;
        }
        if (gtid == 0) { ws->done = 0; ws->err = 1.0; }
    }
    grid.sync();

    double k0sum = 0.0;
    for (int p = 0; p < NBLK; ++p) k0sum += ws->blkpart[p];
    const double W0    = D_MASS / k0sum;
    const double a_sum = ws->a_sum;
    const double b_sum = ws->b_sum;

    // K_t = U[i] * K0[i,j] * V[j] * W  (q1=1/row_prev, q2=1/col_prev, q3=1/scale_prev)
    double W = W0, scale_prev = 1.0, Wp = 0.0;
    int done = 0;

    for (int cpt = 0; cpt < NITER; ++cpt) {
        if (done) break;
        const bool erriter = (cpt % 10) == 0;

        // lazily apply previous iteration's mass-scaling step (W' = s/dot)
        if (cpt > 0) {
            double sd = 0.0;
            for (int p = 0; p < 8; ++p) sd += ws->dotParts[p];
            const double Wq    = W / scale_prev;
            const double scale = D_MASS / (Wq * sd);
            W = D_MASS / sd;          // == Wq * scale
            scale_prev = scale;
        }
        if (erriter) {
            Wp = W;
            if (tid < ROWS_PER_BLK) ws->Up[r0 + tid] = ws->U[r0 + tid];
        }
        __syncthreads();

        // ---- A1: row matvec S_i = sum_j K0[i,j] V[j]; row scaling; U' ----
        for (int rr = wave; rr < ROWS_PER_BLK; rr += 4) {
            const int i = r0 + rr;
            const float* rowp = K + (size_t)i * N;
            double s = 0.0;
            for (int j = lane; j < N; j += 64)
                s += (double)rowp[j] * (double)ws->V[j];
            for (int off = 32; off > 0; off >>= 1) s += __shfl_xor(s, off, 64);
            if (lane == 0) {
                const double Uq     = (double)ws->U[i] / (double)ws->row_prev[i];
                const double rowsum = Uq * W * s;
                const double an     = (double)a[i] / a_sum;
                double r = an / rowsum;
                if (r > 1.0) r = 1.0;
                ws->U[i]        = (float)(Uq * r);
                ws->row_prev[i] = (float)r;
            }
        }
        __syncthreads();

        // ---- A2: per-band column partials T (uses this band's new U') ----
        {
            double ub[ROWS_PER_BLK];
            for (int r = 0; r < ROWS_PER_BLK; ++r) ub[r] = (double)ws->U[r0 + r];
            double acc[COLS_PER_THR];
            for (int c = 0; c < COLS_PER_THR; ++c) acc[c] = 0.0;
            for (int r = 0; r < ROWS_PER_BLK; ++r) {
                const float* rowp = K + (size_t)(r0 + r) * N;
                for (int c = 0; c < COLS_PER_THR; ++c)
                    acc[c] += (double)rowp[tid + NTHR * c] * ub[r];
            }
            for (int c = 0; c < COLS_PER_THR; ++c)
                ws->partialT[(size_t)bid * N + tid + NTHR * c] = (float)acc[c];
        }
        grid.sync();

        // ---- B: reduce T_j, col scaling, V', dot partials ----
        if (bid < 8) {
            const int j = gtid;  // < 2048
            double t = 0.0;
            for (int p = 0; p < NBLK; ++p) t += (double)ws->partialT[(size_t)p * N + j];
            const double Vq     = (double)ws->V[j] / (double)ws->col_prev[j];
            const double colsum = Vq * W * t;
            const double bn     = (double)b[j] / b_sum;
            double cf = bn / colsum;
            if (cf > 1.0) cf = 1.0;
            if (erriter) ws->Vp[j] = ws->V[j];
            const double Vn = Vq * cf;
            ws->V[j]        = (float)Vn;
            ws->col_prev[j] = (float)cf;
            double bsum = block_reduce_sum(t * Vn);
            if (tid == 0) ws->dotParts[bid] = bsum;
        }
        grid.sync();

        if (erriter) {
            // err = || Kprev - Kn ||_F ; Kn uses W' = s/dot of this iteration
            double sd = 0.0;
            for (int p = 0; p < 8; ++p) sd += ws->dotParts[p];
            const double Wn = D_MASS / sd;
            double e2 = 0.0;
            for (int r = 0; r < ROWS_PER_BLK; ++r) {
                const int i = r0 + r;
                const float* rowp = K + (size_t)i * N;
                const double upw = (double)ws->Up[i] * Wp;
                const double unw = (double)ws->U[i] * Wn;
                for (int j = tid; j < N; j += NTHR) {
                    const double d = (double)rowp[j] *
                        (upw * (double)ws->Vp[j] - unw * (double)ws->V[j]);
                    e2 += d * d;
                }
            }
            double be = block_reduce_sum(e2);
            if (tid == 0) ws->errParts[bid] = be;
            grid.sync();
            if (bid == 0) {
                double te = block_reduce_sum(ws->errParts[tid]);
                if (tid == 0) {
                    const double err = sqrt(te);
                    ws->err  = err;
                    ws->done = (err <= D_TOL) ? 1 : 0;
                }
            }
            grid.sync();
            done = *(volatile int*)&ws->done;
        }
    }

    // ---------------- final: K = U[i] * K0[i,j] * V[j] * W' (in place) ----
    {
        double sd = 0.0;
        for (int p = 0; p < 8; ++p) sd += ws->dotParts[p];
        const double Wf = D_MASS / sd;
        for (int r = 0; r < ROWS_PER_BLK; ++r) {
            const int i = r0 + r;
            float* rowp = K + (size_t)i * N;
            const double uf = (double)ws->U[i] * Wf;
            for (int j = tid; j < N; j += NTHR)
                rowp[j] = (float)(uf * (double)rowp[j] * (double)ws->V[j]);
        }
    }
}

extern "C" void kernel_launch(void* const* d_in, const int* in_sizes, int n_in,
                              void* d_out, int out_size, void* d_ws, size_t ws_size,
                              hipStream_t stream) {
    const float* C = (const float*)d_in[0];
    const float* a = (const float*)d_in[1];
    const float* b = (const float*)d_in[2];
    float* K = (float*)d_out;
    Ws*    w = (Ws*)d_ws;
    void* args[5] = { (void*)&C, (void*)&a, (void*)&b, (void*)&K, (void*)&w };
    hipLaunchCooperativeKernel((const void*)epot_kernel, dim3(NBLK), dim3(NTHR),
                               args, 0, stream);
}

// Round 2
// 160.728 us; speedup vs baseline: 1.5382x; 1.5382x over previous
//
#include <hip/hip_runtime.h>
#include <hip/hip_cooperative_groups.h>

namespace cg = cooperative_groups;

static constexpr int    N      = 2048;
static constexpr int    NBLK   = 256;
static constexpr int    NTHR   = 1024;
static constexpr int    RPB    = 8;     // rows per block (band)
static constexpr double D_MASS = 0.9;
static constexpr double D_TOL  = 0.01;
static constexpr int    NITER  = 50;

struct Ws {
    double a_sum, b_sum;
    double errParts[NBLK];
    double dotParts[NBLK];
    double rowSum0[N];
    float  U[N], V[N], Up[N], Vp[N], row_prev[N], col_prev[N];
    float  partialT[NBLK * N];   // 2 MB column partials, [block][col]
};

// all-threads block reduction; every thread returns the full sum
__device__ __forceinline__ double block_reduce(double v, double* s16) {
    for (int off = 32; off; off >>= 1) v += __shfl_xor(v, off, 64);
    const int wave = threadIdx.x >> 6, lane = threadIdx.x & 63;
    __syncthreads();                  // protect s16 reuse
    if (lane == 0) s16[wave] = v;
    __syncthreads();
    double s = 0.0;
    #pragma unroll
    for (int w = 0; w < 16; ++w) s += s16[w];
    return s;
}

__device__ __forceinline__ void row_scale(Ws* ws, const float* a, double a_sum,
                                          double W, int i, double s) {
    const double Uq     = (double)ws->U[i] / (double)ws->row_prev[i];
    const double rowsum = Uq * W * s;
    const double an     = (double)a[i] / a_sum;
    double r = an / rowsum;
    if (r > 1.0) r = 1.0;
    ws->U[i]        = (float)(Uq * r);
    ws->row_prev[i] = (float)r;
}

__global__ void __launch_bounds__(NTHR, 1)
epot_kernel(const float* __restrict__ C, const float* __restrict__ a,
            const float* __restrict__ b, float* __restrict__ K,
            Ws* __restrict__ ws) {
    cg::grid_group grid = cg::this_grid();
    __shared__ double s16[16];
    __shared__ double sred[128][8];
    __shared__ double sdot[8];

    const int tid  = threadIdx.x;
    const int bid  = blockIdx.x;
    const int lane = tid & 63;
    const int r0   = bid * RPB;
    const int rloc = tid >> 7;        // 0..7: row within band (128 thr/row)
    const int cgrp = tid & 127;       // 0..127: column group within row

    // ---- precompute: K0 = exp(-10C) -> K, row sums, a/b sums, init state ----
    {
        const int i = r0 + rloc;
        const float4* c4 = (const float4*)(C + (size_t)i * N);
        float4*       k4 = (float4*)(K + (size_t)i * N);
        double s = 0.0;
        #pragma unroll 4
        for (int j4 = cgrp; j4 < N / 4; j4 += 128) {
            float4 c = c4[j4];
            float4 e;
            e.x = expf(-10.0f * c.x); e.y = expf(-10.0f * c.y);
            e.z = expf(-10.0f * c.z); e.w = expf(-10.0f * c.w);
            k4[j4] = e;
            s += (double)e.x + (double)e.y + (double)e.z + (double)e.w;
        }
        for (int off = 32; off; off >>= 1) s += __shfl_xor(s, off, 64);
        if (lane == 0) s16[tid >> 6] = s;   // each wave is one row (2 waves/row)
        __syncthreads();
        if (tid < RPB) ws->rowSum0[r0 + tid] = s16[2 * tid] + s16[2 * tid + 1];
        if (bid == 0) {
            double v = (double)a[tid] + (double)a[tid + 1024];
            double t = block_reduce(v, s16);
            if (tid == 0) ws->a_sum = t;
        } else if (bid == 1) {
            double v = (double)b[tid] + (double)b[tid + 1024];
            double t = block_reduce(v, s16);
            if (tid == 0) ws->b_sum = t;
        }
        const int g = bid * NTHR + tid;
        if (g < N) {
            ws->U[g] = 1.0f; ws->V[g] = 1.0f;
            ws->row_prev[g] = 1.0f; ws->col_prev[g] = 1.0f;
        }
    }
    grid.sync();

    const double k0sum = block_reduce(ws->rowSum0[tid] + ws->rowSum0[tid + 1024], s16);
    const double a_sum = ws->a_sum, b_sum = ws->b_sum;

    // K_t = U[i] * K0[i,j] * V[j] * W  (q1=1/row_prev, q2=1/col_prev, q3=1/scale_prev)
    double W = D_MASS / k0sum, scale_prev = 1.0, Wp = 0.0;
    bool done = false;

    for (int cpt = 0; cpt < NITER && !done; ++cpt) {
        const bool erriter = (cpt % 10) == 0;

        if (cpt > 0) {   // lazily apply previous iteration's mass scaling
            double dv = (tid < NBLK) ? ws->dotParts[tid] : 0.0;
            const double sd = block_reduce(dv, s16);
            const double Wq = W / scale_prev;
            scale_prev = D_MASS / (Wq * sd);
            W = D_MASS / sd;
        }
        if (erriter) {
            Wp = W;
            if (tid < RPB) ws->Up[r0 + tid] = ws->U[r0 + tid];
        }
        __syncthreads();

        // ---- A1: row sums + row scaling (iter 0 row sums precomputed) ----
        if (cpt == 0) {
            if (tid < RPB) {
                const int i = r0 + tid;
                row_scale(ws, a, a_sum, W, i, ws->rowSum0[i]);
            }
        } else {
            const int i = r0 + rloc;
            const float4* k4 = (const float4*)(K + (size_t)i * N);
            const float4* v4 = (const float4*)ws->V;
            double s = 0.0;
            #pragma unroll 4
            for (int j4 = cgrp; j4 < N / 4; j4 += 128) {
                float4 kk = k4[j4], vv = v4[j4];
                s += (double)kk.x * vv.x + (double)kk.y * vv.y
                   + (double)kk.z * vv.z + (double)kk.w * vv.w;
            }
            for (int off = 32; off; off >>= 1) s += __shfl_xor(s, off, 64);
            if (lane == 0) s16[tid >> 6] = s;
            __syncthreads();
            if (tid < RPB)
                row_scale(ws, a, a_sum, W, r0 + tid, s16[2 * tid] + s16[2 * tid + 1]);
        }
        __syncthreads();

        // ---- A2: band's column partials with new U (coalesced float2) ----
        {
            double ub[RPB];
            #pragma unroll
            for (int r = 0; r < RPB; ++r) ub[r] = (double)ws->U[r0 + r];
            const int j0 = 2 * tid;
            double ax = 0.0, ay = 0.0;
            #pragma unroll
            for (int r = 0; r < RPB; ++r) {
                const float2 kv = *(const float2*)(K + (size_t)(r0 + r) * N + j0);
                ax += (double)kv.x * ub[r];
                ay += (double)kv.y * ub[r];
            }
            float2 o; o.x = (float)ax; o.y = (float)ay;
            *(float2*)(ws->partialT + (size_t)bid * N + j0) = o;
        }
        grid.sync();

        // ---- B: every block reduces its own 8 columns ----
        {
            const int g  = tid >> 3;          // 0..127: partial index pair
            const int jj = tid & 7;
            const int j  = bid * RPB + jj;
            sred[g][jj] = (double)ws->partialT[(size_t)g * N + j]
                        + (double)ws->partialT[(size_t)(g + 128) * N + j];
            __syncthreads();
            for (int s2 = 64; s2 > 0; s2 >>= 1) {
                if (g < s2) sred[g][jj] += sred[g + s2][jj];
                __syncthreads();
            }
            if (tid < RPB) {
                const int jc = bid * RPB + tid;
                const double Tj = sred[0][tid];
                const double Vq = (double)ws->V[jc] / (double)ws->col_prev[jc];
                const double colsum = Vq * W * Tj;
                const double bn = (double)b[jc] / b_sum;
                double cf = bn / colsum;
                if (cf > 1.0) cf = 1.0;
                if (erriter) ws->Vp[jc] = ws->V[jc];
                const double Vn = Vq * cf;
                ws->V[jc]        = (float)Vn;
                ws->col_prev[jc] = (float)cf;
                sdot[tid] = Tj * Vn;
            }
            __syncthreads();
            if (tid == 0) {
                double d = 0.0;
                #pragma unroll
                for (int q = 0; q < RPB; ++q) d += sdot[q];
                ws->dotParts[bid] = d;
            }
        }
        grid.sync();

        // ---- error check (every 10 iters); each block reduces redundantly ----
        if (erriter) {
            double dv = (tid < NBLK) ? ws->dotParts[tid] : 0.0;
            const double sd = block_reduce(dv, s16);
            const double Wn = D_MASS / sd;
            const int i = r0 + rloc;
            const double upw = (double)ws->Up[i] * Wp;
            const double unw = (double)ws->U[i] * Wn;
            const float4* k4  = (const float4*)(K + (size_t)i * N);
            const float4* vp4 = (const float4*)ws->Vp;
            const float4* vn4 = (const float4*)ws->V;
            double e2 = 0.0;
            #pragma unroll 4
            for (int j4 = cgrp; j4 < N / 4; j4 += 128) {
                float4 kk = k4[j4], vp = vp4[j4], vn = vn4[j4];
                double d;
                d = (double)kk.x * (upw * (double)vp.x - unw * (double)vn.x); e2 += d * d;
                d = (double)kk.y * (upw * (double)vp.y - unw * (double)vn.y); e2 += d * d;
                d = (double)kk.z * (upw * (double)vp.z - unw * (double)vn.z); e2 += d * d;
                d = (double)kk.w * (upw * (double)vp.w - unw * (double)vn.w); e2 += d * d;
            }
            const double be = block_reduce(e2, s16);
            if (tid == 0) ws->errParts[bid] = be;
            grid.sync();
            double ev = (tid < NBLK) ? ws->errParts[tid] : 0.0;
            const double te = block_reduce(ev, s16);
            done = (sqrt(te) <= D_TOL);   // bitwise-identical in every block
        }
    }

    // ---- final: K = U[i] * K0[i,j] * V[j] * W_final, in place ----
    {
        double dv = (tid < NBLK) ? ws->dotParts[tid] : 0.0;
        const double sd = block_reduce(dv, s16);
        const double Wf = D_MASS / sd;
        const int i = r0 + rloc;
        const double uf = (double)ws->U[i] * Wf;
        float4*       k4 = (float4*)(K + (size_t)i * N);
        const float4* v4 = (const float4*)ws->V;
        #pragma unroll 4
        for (int j4 = cgrp; j4 < N / 4; j4 += 128) {
            float4 kk = k4[j4], vv = v4[j4];
            kk.x = (float)(uf * (double)kk.x * (double)vv.x);
            kk.y = (float)(uf * (double)kk.y * (double)vv.y);
            kk.z = (float)(uf * (double)kk.z * (double)vv.z);
            kk.w = (float)(uf * (double)kk.w * (double)vv.w);
            k4[j4] = kk;
        }
    }
}

extern "C" void kernel_launch(void* const* d_in, const int* in_sizes, int n_in,
                              void* d_out, int out_size, void* d_ws, size_t ws_size,
                              hipStream_t stream) {
    const float* C = (const float*)d_in[0];
    const float* a = (const float*)d_in[1];
    const float* b = (const float*)d_in[2];
    float* K = (float*)d_out;
    Ws*    w = (Ws*)d_ws;
    void* args[5] = { (void*)&C, (void*)&a, (void*)&b, (void*)&K, (void*)&w };
    hipLaunchCooperativeKernel((const void*)epot_kernel, dim3(NBLK), dim3(NTHR),
                               args, 0, stream);
}